// Round 4
// baseline (177.148 us; speedup 1.0000x reference)
//
#include <hip/hip_runtime.h>
#include <math.h>

// Problem constants (from reference setup_inputs): B=4, C=32, H=W=256, out-ch=32
#define B_N 4
#define C_N 32
#define H_N 256
#define W_N 256
#define PI_D 3.14159265358979323846
#define CR   18   // float2 row stride of 8-row half-matrix (144 B, 16B-aligned)
#define SEQS 146  // float2 stride per sequence region (8*CR=144 +2: seq bank rotate)
#define LTS  36   // float stride for K1 row-major staging tile (aliases matrices)
#define FTS  36   // uint (half2) stride for K2 feat buffer rows (aliases matrices)
#define OBS  34   // float2 stride for K1 half-tile out buffer (aliases matrices)
#define LDW  260  // float stride for K2 out-transpose buffer (aliases matrices)

typedef _Float16 half8 __attribute__((ext_vector_type(8)));
typedef float f32x4 __attribute__((ext_vector_type(4)));

union H2U { unsigned int u; struct { _Float16 lo, hi; } f; };

__device__ __forceinline__ float2 cmul(float2 a, float2 b) {
    return make_float2(a.x * b.x - a.y * b.y, a.x * b.y + a.y * b.x);
}
__device__ __forceinline__ float2 f2add(float2 a, float2 b) {
    return make_float2(a.x + b.x, a.y + b.y);
}
__device__ __forceinline__ float2 f2sub(float2 a, float2 b) {
    return make_float2(a.x - b.x, a.y - b.y);
}

// ---------------- per-block chirp/twiddle tables (all-f32) -------------------
__device__ __forceinline__ void make_tables(int tid, const float* __restrict__ alpha_p,
                                            float2* c1l, float2* c2l, float2* twl,
                                            float* sscl) {
    if (tid < 256) {
        int j = tid;
        float a = fminf(fmaxf(alpha_p[0], 1e-4f), 2.0f - 1e-4f);
        float tan_a2 = tanf(a * (float)(PI_D / 4.0));
        float sin_a  = sinf(a * (float)(PI_D / 2.0));   // > 0 for a in (0,2)
        float n = (float)(j - 128);
        float n2f = n * n;                               // <= 16384, exact
        float sn, cs;

        float u1 = n2f * tan_a2 * (1.0f / 256.0f);       // phase = -pi*u1
        u1 -= 2.0f * floorf(u1 * 0.5f);                  // mod 2
        __sincosf(-(float)PI_D * u1, &sn, &cs);
        c1l[j] = make_float2(cs, sn);

        float u2 = n2f / (256.0f * sin_a);
        u2 -= 2.0f * floorf(u2 * 0.5f);
        __sincosf(-(float)PI_D * u2, &sn, &cs);
        c2l[j] = make_float2(cs, sn);

        int k1 = j >> 4, t = j & 15;
        __sincosf(-(float)(2.0 * PI_D / 256.0) * (float)(t * k1), &sn, &cs);
        twl[j] = make_float2(cs, sn);

        if (j == 0) *sscl = 1.0f / sqrtf(sin_a + 1e-12f);
    }
}

// ---------------- FFT16 in registers (radix-4 x radix-4) ---------------------
// Input: v[n] natural order. Output: v[4*(k&3) + (k>>2)] = F[k].
template <bool INV>
__device__ __forceinline__ void fft16(float2* v) {
    const float C1 = 0.9238795325112867f, S1 = 0.3826834323650898f;
    const float C2 = 0.7071067811865476f;
    const float2 tw1 = make_float2(C1, INV ? S1 : -S1);
    const float2 tw2 = make_float2(C2, INV ? C2 : -C2);
    const float2 tw3 = make_float2(S1, INV ? C1 : -C1);
    const float2 tw4 = make_float2(0.0f, INV ? 1.0f : -1.0f);
    const float2 tw6 = make_float2(-C2, INV ? C2 : -C2);
    const float2 tw9 = make_float2(-C1, INV ? -S1 : S1);
    float2 u[16];
    #pragma unroll
    for (int n2 = 0; n2 < 4; ++n2) {
        float2 e0 = v[n2], e1 = v[4 + n2], e2 = v[8 + n2], e3 = v[12 + n2];
        float2 t0 = f2add(e0, e2), t1 = f2sub(e0, e2);
        float2 t2 = f2add(e1, e3), t3 = f2sub(e1, e3);
        float2 A0 = f2add(t0, t2);
        float2 A2 = f2sub(t0, t2);
        float2 A1, A3;
        if (!INV) { A1 = make_float2(t1.x + t3.y, t1.y - t3.x);
                    A3 = make_float2(t1.x - t3.y, t1.y + t3.x); }
        else      { A1 = make_float2(t1.x - t3.y, t1.y + t3.x);
                    A3 = make_float2(t1.x + t3.y, t1.y - t3.x); }
        u[n2] = A0;
        if (n2 == 0) { u[4 + n2] = A1;            u[8 + n2] = A2;            u[12 + n2] = A3; }
        if (n2 == 1) { u[4 + n2] = cmul(A1, tw1); u[8 + n2] = cmul(A2, tw2); u[12 + n2] = cmul(A3, tw3); }
        if (n2 == 2) { u[4 + n2] = cmul(A1, tw2); u[8 + n2] = cmul(A2, tw4); u[12 + n2] = cmul(A3, tw6); }
        if (n2 == 3) { u[4 + n2] = cmul(A1, tw3); u[8 + n2] = cmul(A2, tw6); u[12 + n2] = cmul(A3, tw9); }
    }
    #pragma unroll
    for (int k1 = 0; k1 < 4; ++k1) {
        float2 e0 = u[4 * k1], e1 = u[4 * k1 + 1], e2 = u[4 * k1 + 2], e3 = u[4 * k1 + 3];
        float2 t0 = f2add(e0, e2), t1 = f2sub(e0, e2);
        float2 t2 = f2add(e1, e3), t3 = f2sub(e1, e3);
        v[4 * k1 + 0] = f2add(t0, t2);
        v[4 * k1 + 2] = f2sub(t0, t2);
        if (!INV) { v[4 * k1 + 1] = make_float2(t1.x + t3.y, t1.y - t3.x);
                    v[4 * k1 + 3] = make_float2(t1.x - t3.y, t1.y + t3.x); }
        else      { v[4 * k1 + 1] = make_float2(t1.x - t3.y, t1.y + t3.x);
                    v[4 * k1 + 3] = make_float2(t1.x + t3.y, t1.y - t3.x); }
    }
}
#define REG(k) (4 * ((k) & 3) + ((k) >> 2))

// row-contiguous 16-float2 LDS read as 8x ds_read_b128 (rp is 16B-aligned)
__device__ __forceinline__ void lds_read_row16(const float2* __restrict__ rp, float2* v) {
    #pragma unroll
    for (int c = 0; c < 8; ++c) {
        f32x4 r = *(const f32x4*)(rp + 2 * c);
        v[2 * c]     = make_float2(r.x, r.y);
        v[2 * c + 1] = make_float2(r.z, r.w);
    }
}

// ---------------- 16x16 wave-local transpose via 8-row ping-pong -------------
// Lane c holds column c (a[r] = M[r][c], natural index). Output: o[n] = M[t][n].
// Only an 8-row half-matrix is live at any time (rows stored at r&7), halving
// the LDS footprint (44KB block -> 3 blocks/CU vs 2).
// Safety: the seq's 16 lanes are lockstep in ONE wave; LDS ops execute in
// issue order, so phase-A reads (t<8) complete before phase-B overwrites.
__device__ __forceinline__ void xpose16(const float2* a, float2* o,
                                        float2* __restrict__ sp, int t) {
    bool lo = (t & 8) == 0;
    float2* rp = sp + CR * (t & 7);
    #pragma unroll
    for (int r = 0; r < 8; ++r) sp[CR * r + t] = a[r];        // rows 0..7
    __builtin_amdgcn_wave_barrier();
    if (lo) lds_read_row16(rp, o);
    __builtin_amdgcn_wave_barrier();
    #pragma unroll
    for (int r = 0; r < 8; ++r) sp[CR * r + t] = a[8 + r];    // rows 8..15
    __builtin_amdgcn_wave_barrier();
    if (!lo) lds_read_row16(rp, o);
    __builtin_amdgcn_wave_barrier();
}

// ---------------- FRFT core: 256-pt via four-step radix-16 -------------------
// In: v[n1] = x[16*n1 + t] * c1[16*n1 + t]. Out: v[REG(m1)] = z[16*m1 + t].
// sp: this sequence's 8xCR half-matrix region. Fully wave-local (no s_barrier).
__device__ __forceinline__ void frft_core16(float2* v, float2* __restrict__ sp,
                                            int t,
                                            const float2* __restrict__ c2l,
                                            const float2* __restrict__ twl) {
    fft16<false>(v);  // over n1 -> A[k1] at v[REG(k1)]
    float2 w[16];
    #pragma unroll
    for (int k1 = 0; k1 < 16; ++k1)
        w[k1] = cmul(v[REG(k1)], twl[16 * k1 + t]);   // * W256^{t*k1}
    xpose16(w, v, sp, t);                             // v[n2] = M[t][n2]
    fft16<false>(v);  // over n2 -> B[k2] = X[t + 16*k2] at v[REG(k2)]
    #pragma unroll
    for (int k2 = 0; k2 < 16; ++k2)
        w[k2] = cmul(v[REG(k2)], c2l[t + 16 * k2]);   // mid: * c2
    fft16<true>(w);   // over k2 -> C[m2] at w[REG(m2)]
    #pragma unroll
    for (int m2 = 0; m2 < 16; ++m2) {
        float2 tw = twl[16 * m2 + t];
        tw.y = -tw.y;                                 // W256^{+t*m2}
        v[m2] = cmul(w[REG(m2)], tw);
    }
    xpose16(v, w, sp, t);
    fft16<true>(w);   // over k1 -> z[16*m1 + t] at w[REG(m1)]
    #pragma unroll
    for (int i = 0; i < 16; ++i) v[i] = w[i];         // register rename, free
}

// ---------------- K1: FRFT along H on REAL input x -> Y ----------------------
// 32 columns per block, 1024 blocks, 512 threads = 32 seqs x 16 t (wave-local).
// LDS ~43.5KB -> 3 blocks/CU. Y stores go through a two-phase half-tile LDS
// reshape (aliases dead matrices) so each wave stores 256B-contiguous chunks —
// round 3's direct strided stores caused 1.76x HBM write amplification.
__global__ __launch_bounds__(512, 6) void frft_cols_real(
        const float* __restrict__ x,
        const float* __restrict__ alpha_p,
        float2* __restrict__ Y) {
    __shared__ float2 s[32 * SEQS];                // 37.4 KB; aliased 3 ways
    __shared__ float2 c1l[256], c2l[256], twl[256];
    __shared__ float sscl;
    int tid = threadIdx.x;

    int blk = blockIdx.x;
    int w0 = (blk & 7) << 5;                       // 32-col tile
    long long bc = blk >> 3;
    const float* xb = x + (bc << 16) + w0;

    // issue coalesced loads first (latency overlapped by table compute)
    f32x4 xv[4];
    #pragma unroll
    for (int p = 0; p < 4; ++p) {
        int idx = tid + (p << 9);                  // 0..2047
        int row = idx >> 3, c4 = idx & 7;
        xv[p] = __builtin_nontemporal_load((const f32x4*)(xb + row * W_N + (c4 << 2)));
    }

    make_tables(tid, alpha_p, c1l, c2l, twl, &sscl);

    // stage tile row-major into LDS (float4 writes)
    float* fs = (float*)s;
    #pragma unroll
    for (int p = 0; p < 4; ++p) {
        int idx = tid + (p << 9);
        int row = idx >> 3, c4 = idx & 7;
        *(f32x4*)&fs[row * LTS + (c4 << 2)] = xv[p];
    }
    __syncthreads();

    int t = tid & 15, seq = tid >> 4;              // wave-local: 4 seqs per wave
    float xs[16];
    #pragma unroll
    for (int n1 = 0; n1 < 16; ++n1)
        xs[n1] = fs[(16 * (n1 ^ 8) + t) * LTS + seq];  // ifftshift, column read
    float scl_v = sscl;
    __syncthreads();                               // staging reads done before core writes

    float2 v[16];
    #pragma unroll
    for (int n1 = 0; n1 < 16; ++n1) {
        float2 c = c1l[16 * n1 + t];
        v[n1] = make_float2(xs[n1] * c.x, xs[n1] * c.y);
    }

    frft_core16(v, s + seq * SEQS, t, c2l, twl);

    // ---- coalesced Y store via two half-tile (128 rows) LDS reshapes ----
    // half 0: output rows 0..127  = m1 in 8..15 (16*(m1^8)+t = 16*(m1&7)+t)
    // half 1: output rows 128..255 = m1 in 0..7
    float sc = scl_v * (1.0f / 256.0f);
    float2* ob = s;                                // alias: [128][OBS] float2
    int orow = tid >> 2, oc8 = (tid & 3) * 8;
    float2* Yb = Y + (bc << 16) + w0;
    #pragma unroll
    for (int half = 0; half < 2; ++half) {
        __syncthreads();   // core / previous-phase LDS reads done before overwrite
        #pragma unroll
        for (int j = 0; j < 8; ++j) {
            int m1 = half ? j : (8 + j);
            float2 o = cmul(v[REG(m1)], c1l[16 * m1 + t]);
            ob[(16 * j + t) * OBS + seq] = make_float2(o.x * sc, o.y * sc);
        }
        __syncthreads();
        f32x4 r0 = *(const f32x4*)&ob[orow * OBS + oc8];
        f32x4 r1 = *(const f32x4*)&ob[orow * OBS + oc8 + 2];
        f32x4 r2 = *(const f32x4*)&ob[orow * OBS + oc8 + 4];
        f32x4 r3 = *(const f32x4*)&ob[orow * OBS + oc8 + 6];
        float2* yp = Yb + (half * 128 + orow) * W_N + oc8;
        *(f32x4*)(yp)     = r0;
        *(f32x4*)(yp + 2) = r1;
        *(f32x4*)(yp + 4) = r2;
        *(f32x4*)(yp + 6) = r3;
    }
}

// ---------------- K2: FRFT along W fused with mag/ang + MFMA 1x1 conv --------
// One block per (b,h): 512 threads = 32 channels x 16 t (wave-local core).
// feat buffer = packed half2(mag, ang/pi) [256 pix][FTS] aliased over dead
// matrices; MFMA D goes through the Ob LDS transpose (aliased over dead feat)
// for 256B-coalesced stores — round 3's direct scattered stores caused 2.9x
// HBM write amplification.
__device__ __forceinline__ float fast_atan2(float y, float x) {
    float ax = fabsf(x), ay = fabsf(y);
    float mx = fmaxf(ax, ay), mn = fminf(ax, ay);
    float z = mn * __builtin_amdgcn_rcpf(fmaxf(mx, 1e-37f));
    float z2 = z * z;
    float p = fmaf(z2, -0.01172120f, 0.05265332f);
    p = fmaf(z2, p, -0.11643287f);
    p = fmaf(z2, p, 0.19354346f);
    p = fmaf(z2, p, -0.33262347f);
    p = fmaf(z2, p, 0.99997726f);
    p = p * z;
    float r = (ay > ax) ? (1.5707963f - p) : p;
    r = (x < 0.0f) ? (3.14159265f - r) : r;
    return copysignf(r, y);
}

__global__ __launch_bounds__(512, 6) void frft_rows_conv(
        const float2* __restrict__ Y,
        const float* __restrict__ alpha_p,
        const float* __restrict__ wmat, float* __restrict__ out) {
    __shared__ float2 s[32 * SEQS];   // half-matrices -> feat -> Ob (aliased)
    __shared__ float2 c1l[256], c2l[256], twl[256];
    __shared__ float sscl;
    int tid = threadIdx.x;
    int t = tid & 15, ch = tid >> 4;  // seq's 16 t-threads within one wave

    int b = blockIdx.x >> 8, h = blockIdx.x & 255;
    const float2* xr = Y + (((long long)(b * C_N + ch)) << 16) + (h << 8);

    float2 v[16];
    #pragma unroll
    for (int n1 = 0; n1 < 16; ++n1)
        v[n1] = xr[16 * (n1 ^ 8) + t];   // ifftshift along W

    make_tables(tid, alpha_p, c1l, c2l, twl, &sscl);
    __syncthreads();                     // tables ready

    #pragma unroll
    for (int n1 = 0; n1 < 16; ++n1)
        v[n1] = cmul(v[n1], c1l[16 * n1 + t]);

    frft_core16(v, s + ch * SEQS, t, c2l, twl);

    // mag/ang in registers, packed to half2 (same values MFMA consumed before)
    float sc = sscl * (1.0f / 256.0f);
    unsigned int pk[16];
    #pragma unroll
    for (int m1 = 0; m1 < 16; ++m1) {
        float2 o = cmul(v[REG(m1)], c1l[16 * m1 + t]);
        float mg = sc * sqrtf(fmaf(o.x, o.x, o.y * o.y));
        float an = fast_atan2(o.y, o.x) * 0.31830988618f;
        H2U pu; pu.f.lo = (_Float16)mg; pu.f.hi = (_Float16)an;
        pk[m1] = pu.u;
    }
    __syncthreads();                  // all cores done: matrix region dead

    unsigned int* feat = (unsigned int*)s;   // half2 per (pixel, channel)
    #pragma unroll
    for (int m1 = 0; m1 < 16; ++m1)
        feat[(16 * (m1 ^ 8) + t) * FTS + ch] = pk[m1];   // pixel-major rows
    __syncthreads();                  // feat ready for all waves

    // ---- MFMA conv phase ----
    int lane = tid & 63, wv = tid >> 6;
    int q = lane >> 4, l15 = lane & 15;

    // B fragments from global (L2-hot 8KB), f16
    half8 bf[2][2];
    #pragma unroll
    for (int nt = 0; nt < 2; ++nt)
        #pragma unroll
        for (int kt = 0; kt < 2; ++kt) {
            const float* wp = wmat + (nt * 16 + l15) * 64 + kt * 32 + q * 8;
            float4 wa = *(const float4*)wp;
            float4 wb = *(const float4*)(wp + 4);
            bf[nt][kt][0] = (_Float16)wa.x; bf[nt][kt][1] = (_Float16)wa.y;
            bf[nt][kt][2] = (_Float16)wa.z; bf[nt][kt][3] = (_Float16)wa.w;
            bf[nt][kt][4] = (_Float16)wb.x; bf[nt][kt][5] = (_Float16)wb.y;
            bf[nt][kt][6] = (_Float16)wb.z; bf[nt][kt][7] = (_Float16)wb.w;
        }

    f32x4 acc[2][2];
    #pragma unroll
    for (int i = 0; i < 2; ++i)
        #pragma unroll
        for (int j = 0; j < 2; ++j)
            acc[i][j] = (f32x4){0.0f, 0.0f, 0.0f, 0.0f};

    #pragma unroll
    for (int mt2 = 0; mt2 < 2; ++mt2) {
        int mt = wv * 2 + mt2;
        int w = mt * 16 + l15;
        // 8 channels' (mag,ang) at pixel w: 2x ds_read_b128
        const uint4* fp = (const uint4*)(feat + w * FTS + q * 8);
        uint4 ca = fp[0], cb = fp[1];
        half8 am, aa;
        #pragma unroll
        for (int j = 0; j < 8; ++j) {
            H2U pu;
            pu.u = (j < 4) ? ((const unsigned int*)&ca)[j]
                           : ((const unsigned int*)&cb)[j - 4];
            am[j] = pu.f.lo;                        // mag -> k = q*8+j
            aa[j] = pu.f.hi;                        // ang -> k = 32 + q*8+j
        }
        #pragma unroll
        for (int nt = 0; nt < 2; ++nt) {
            acc[mt2][nt] = __builtin_amdgcn_mfma_f32_16x16x32_f16(am, bf[nt][0], acc[mt2][nt], 0, 0, 0);
            acc[mt2][nt] = __builtin_amdgcn_mfma_f32_16x16x32_f16(aa, bf[nt][1], acc[mt2][nt], 0, 0, 0);
        }
    }
    __syncthreads();   // all feat reads done before Ob overwrites s

    // D -> LDS transpose buffer Ob[o][w] (aliases dead feat region)
    float* Ob = (float*)s;
    #pragma unroll
    for (int mt2 = 0; mt2 < 2; ++mt2) {
        int mt = wv * 2 + mt2;
        #pragma unroll
        for (int nt = 0; nt < 2; ++nt) {
            int o = nt * 16 + l15;
            *(f32x4*)&Ob[o * LDW + mt * 16 + q * 4] = acc[mt2][nt];
        }
    }
    __syncthreads();

    // coalesced stores: thread -> (o = tid>>4, 4 float4 chunks along w)
    int o2 = tid >> 4, i16 = tid & 15;
    float* ob = out + (((long long)(b * C_N + o2)) << 16) + (h << 8);
    #pragma unroll
    for (int p = 0; p < 4; ++p) {
        int w4 = i16 * 4 + (p << 6);
        f32x4 val = *(f32x4*)&Ob[o2 * LDW + w4];
        *(f32x4*)(ob + w4) = val;
    }
}

// ---------------- launch -----------------------------------------------------
extern "C" void kernel_launch(void* const* d_in, const int* in_sizes, int n_in,
                              void* d_out, int out_size, void* d_ws, size_t ws_size,
                              hipStream_t stream) {
    const float* x     = (const float*)d_in[0];
    const float* alpha = (const float*)d_in[1];
    const float* wmat  = (const float*)d_in[2];
    float* out = (float*)d_out;

    float2* Y = (float2*)d_ws;   // 64 MiB intermediate (H-pass output)

    // Pass 1: FRFT along H on real input (order commutes with W pass).
    frft_cols_real<<<B_N * C_N * (W_N / 32), 512, 0, stream>>>(x, alpha, Y);

    // Pass 2: FRFT along W + magnitude/phase + MFMA 1x1 conv, fused per (b,h).
    frft_rows_conv<<<B_N * H_N, 512, 0, stream>>>(Y, alpha, wmat, out);
}

// Round 5
// 125.367 us; speedup vs baseline: 1.4130x; 1.4130x over previous
//
#include <hip/hip_runtime.h>
#include <math.h>

// Problem constants (from reference setup_inputs): B=4, C=32, H=W=256
#define B_N 4
#define C_N 32
#define H_N 256
#define W_N 256
#define PI_D 3.14159265358979323846
#define LSQ 257   // float2 stride per sequence region in LDS
#define LDW 260   // float stride for out-transpose buffer (reuses s)

typedef _Float16 half8 __attribute__((ext_vector_type(8)));
typedef float f32x4 __attribute__((ext_vector_type(4)));

union H2U { unsigned int u; struct { _Float16 lo, hi; } f; };

__device__ __forceinline__ float2 cmul(float2 a, float2 b) {
    return make_float2(a.x * b.x - a.y * b.y, a.x * b.y + a.y * b.x);
}
__device__ __forceinline__ float2 f2add(float2 a, float2 b) {
    return make_float2(a.x + b.x, a.y + b.y);
}
__device__ __forceinline__ float2 f2sub(float2 a, float2 b) {
    return make_float2(a.x - b.x, a.y - b.y);
}

// ---------------- per-block chirp/twiddle tables (all-f32) -------------------
// f32 tan/sin: phase error <= ~3e-5 rad; measured absmax-neutral (R1).
__device__ __forceinline__ void make_tables(int tid, const float* __restrict__ alpha_p,
                                            float2* c1l, float2* c2l, float2* twl,
                                            float* sscl) {
    if (tid < 256) {
        int j = tid;
        float a = fminf(fmaxf(alpha_p[0], 1e-4f), 2.0f - 1e-4f);
        float tan_a2 = tanf(a * (float)(PI_D / 4.0));
        float sin_a  = sinf(a * (float)(PI_D / 2.0));   // > 0 for a in (0,2)
        float n = (float)(j - 128);
        float n2f = n * n;                               // <= 16384, exact
        float sn, cs;

        float u1 = n2f * tan_a2 * (1.0f / 256.0f);       // phase = -pi*u1
        u1 -= 2.0f * floorf(u1 * 0.5f);                  // mod 2
        __sincosf(-(float)PI_D * u1, &sn, &cs);
        c1l[j] = make_float2(cs, sn);

        float u2 = n2f / (256.0f * sin_a);
        u2 -= 2.0f * floorf(u2 * 0.5f);
        __sincosf(-(float)PI_D * u2, &sn, &cs);
        c2l[j] = make_float2(cs, sn);

        int k1 = j >> 4, t = j & 15;
        __sincosf(-(float)(2.0 * PI_D / 256.0) * (float)(t * k1), &sn, &cs);
        twl[j] = make_float2(cs, sn);

        if (j == 0) *sscl = 1.0f / sqrtf(sin_a + 1e-12f);
    }
}

// ---------------- FFT16 in registers (radix-4 x radix-4) ---------------------
// Input: v[n] natural order. Output: v[4*(k&3) + (k>>2)] = F[k].
template <bool INV>
__device__ __forceinline__ void fft16(float2* v) {
    const float C1 = 0.9238795325112867f, S1 = 0.3826834323650898f;
    const float C2 = 0.7071067811865476f;
    const float2 tw1 = make_float2(C1, INV ? S1 : -S1);
    const float2 tw2 = make_float2(C2, INV ? C2 : -C2);
    const float2 tw3 = make_float2(S1, INV ? C1 : -C1);
    const float2 tw4 = make_float2(0.0f, INV ? 1.0f : -1.0f);
    const float2 tw6 = make_float2(-C2, INV ? C2 : -C2);
    const float2 tw9 = make_float2(-C1, INV ? -S1 : S1);
    float2 u[16];
    #pragma unroll
    for (int n2 = 0; n2 < 4; ++n2) {
        float2 e0 = v[n2], e1 = v[4 + n2], e2 = v[8 + n2], e3 = v[12 + n2];
        float2 t0 = f2add(e0, e2), t1 = f2sub(e0, e2);
        float2 t2 = f2add(e1, e3), t3 = f2sub(e1, e3);
        float2 A0 = f2add(t0, t2);
        float2 A2 = f2sub(t0, t2);
        float2 A1, A3;
        if (!INV) { A1 = make_float2(t1.x + t3.y, t1.y - t3.x);
                    A3 = make_float2(t1.x - t3.y, t1.y + t3.x); }
        else      { A1 = make_float2(t1.x - t3.y, t1.y + t3.x);
                    A3 = make_float2(t1.x + t3.y, t1.y - t3.x); }
        u[n2] = A0;
        if (n2 == 0) { u[4 + n2] = A1;            u[8 + n2] = A2;            u[12 + n2] = A3; }
        if (n2 == 1) { u[4 + n2] = cmul(A1, tw1); u[8 + n2] = cmul(A2, tw2); u[12 + n2] = cmul(A3, tw3); }
        if (n2 == 2) { u[4 + n2] = cmul(A1, tw2); u[8 + n2] = cmul(A2, tw4); u[12 + n2] = cmul(A3, tw6); }
        if (n2 == 3) { u[4 + n2] = cmul(A1, tw3); u[8 + n2] = cmul(A2, tw6); u[12 + n2] = cmul(A3, tw9); }
    }
    #pragma unroll
    for (int k1 = 0; k1 < 4; ++k1) {
        float2 e0 = u[4 * k1], e1 = u[4 * k1 + 1], e2 = u[4 * k1 + 2], e3 = u[4 * k1 + 3];
        float2 t0 = f2add(e0, e2), t1 = f2sub(e0, e2);
        float2 t2 = f2add(e1, e3), t3 = f2sub(e1, e3);
        v[4 * k1 + 0] = f2add(t0, t2);
        v[4 * k1 + 2] = f2sub(t0, t2);
        if (!INV) { v[4 * k1 + 1] = make_float2(t1.x + t3.y, t1.y - t3.x);
                    v[4 * k1 + 3] = make_float2(t1.x - t3.y, t1.y + t3.x); }
        else      { v[4 * k1 + 1] = make_float2(t1.x - t3.y, t1.y + t3.x);
                    v[4 * k1 + 3] = make_float2(t1.x + t3.y, t1.y - t3.x); }
    }
}
#define REG(k) (4 * ((k) & 3) + ((k) >> 2))

// ---------------- FRFT core: 256-pt via four-step radix-16 -------------------
// In: v[n1] = x[16*n1 + t] * c1[16*n1 + t]. Out: v[REG(m1)] = z[16*m1 + t],
// z = ifft( fft(x*c1) * c2 ) * 256 (caller applies 1/256 in scale).
// sp: this sequence's 16x16 LDS matrix (XOR swizzle: (r,c) at sp[16r + (c^r)]).
__device__ __forceinline__ void frft_core16(float2* v, float2* __restrict__ sp,
                                            int t,
                                            const float2* __restrict__ c2l,
                                            const float2* __restrict__ twl) {
    fft16<false>(v);  // over n1 -> A[k1] at v[REG(k1)]
    float2 w[16];
    #pragma unroll
    for (int k1 = 0; k1 < 16; ++k1)
        w[k1] = cmul(v[REG(k1)], twl[16 * k1 + t]);   // * W256^{t*k1}
    #pragma unroll
    for (int k1 = 0; k1 < 16; ++k1)
        sp[16 * k1 + (t ^ k1)] = w[k1];               // M[k1][t]
    __syncthreads();
    #pragma unroll
    for (int n2 = 0; n2 < 16; ++n2)
        v[n2] = sp[16 * t + (n2 ^ t)];                // M[t][n2]
    fft16<false>(v);  // over n2 -> B[k2] = X[t + 16*k2] at v[REG(k2)]
    #pragma unroll
    for (int k2 = 0; k2 < 16; ++k2)
        w[k2] = cmul(v[REG(k2)], c2l[t + 16 * k2]);   // mid: * c2
    fft16<true>(w);   // over k2 -> C[m2] at w[REG(m2)]
    __syncthreads();  // all phase-1 reads done before overwrite
    #pragma unroll
    for (int m2 = 0; m2 < 16; ++m2) {
        float2 tw = twl[16 * m2 + t];
        tw.y = -tw.y;                                 // W256^{+t*m2}
        sp[16 * m2 + (t ^ m2)] = cmul(w[REG(m2)], tw);
    }
    __syncthreads();
    #pragma unroll
    for (int k1 = 0; k1 < 16; ++k1)
        v[k1] = sp[16 * t + (k1 ^ t)];
    fft16<true>(v);   // over k1 -> z[16*m1 + t] at v[REG(m1)]
}

// ---------------- K1: FRFT along H on REAL input x -> Y (packed f16) ---------
// 32 columns per block, 512 threads. Input staged via coalesced float4 loads
// into LDS dword slots; compute phase reads LDS. Y stored as half2 (re,im):
// halves the intermediate's HBM write stream (67 -> 33.5 MB).
__global__ __launch_bounds__(512, 4) void frft_cols_real(
        const float* __restrict__ x,
        const float* __restrict__ alpha_p,
        unsigned int* __restrict__ Yh) {
    __shared__ float2 s[32 * LSQ];                 // 65.8 KB
    __shared__ float2 c1l[256], c2l[256], twl[256];
    __shared__ float sscl;
    int tid = threadIdx.x;

    int blk = blockIdx.x;
    int w0 = (blk & 7) << 5;                       // 32-col tile
    long long bc = blk >> 3;
    const float* xb = x + (bc << 16) + w0;

    // issue coalesced loads first (latency overlapped by table compute)
    float4 xv[4];
    #pragma unroll
    for (int p = 0; p < 4; ++p) {
        int idx = tid + (p << 9);                  // 0..2047
        int row = idx >> 3, c4 = idx & 7;
        xv[p] = *(const float4*)(xb + row * W_N + (c4 << 2));
    }

    make_tables(tid, alpha_p, c1l, c2l, twl, &sscl);

    // stage tile into LDS (dword view of s)
    float* fs = (float*)s;
    #pragma unroll
    for (int p = 0; p < 4; ++p) {
        int idx = tid + (p << 9);
        int row = idx >> 3, c4 = idx & 7;
        fs[(4 * c4 + 0) * (2 * LSQ) + row] = xv[p].x;
        fs[(4 * c4 + 1) * (2 * LSQ) + row] = xv[p].y;
        fs[(4 * c4 + 2) * (2 * LSQ) + row] = xv[p].z;
        fs[(4 * c4 + 3) * (2 * LSQ) + row] = xv[p].w;
    }
    __syncthreads();

    int seq = tid & 31, t = tid >> 5;              // 32 seqs x 16 t-groups
    float xs[16];
    #pragma unroll
    for (int n1 = 0; n1 < 16; ++n1)
        xs[n1] = fs[seq * (2 * LSQ) + 16 * (n1 ^ 8) + t];  // ifftshift
    float scl_v = sscl;
    __syncthreads();                               // staging reads done before core writes

    float2 v[16];
    #pragma unroll
    for (int n1 = 0; n1 < 16; ++n1) {
        float2 c = c1l[16 * n1 + t];
        v[n1] = make_float2(xs[n1] * c.x, xs[n1] * c.y);
    }

    frft_core16(v, s + seq * LSQ, t, c2l, twl);

    float sc = scl_v * (1.0f / 256.0f);
    unsigned int* Yb = Yh + (bc << 16) + w0 + seq;
    #pragma unroll
    for (int m1 = 0; m1 < 16; ++m1) {
        float2 o = cmul(v[REG(m1)], c1l[16 * m1 + t]);
        H2U pu;
        pu.f.lo = (_Float16)(o.x * sc);
        pu.f.hi = (_Float16)(o.y * sc);
        Yb[(16 * (m1 ^ 8) + t) * W_N] = pu.u;      // fftshift; 128B/row-half per wave
    }
}

// ---------------- K2: FRFT along W fused with mag/ang + MFMA 1x1 conv --------
// One block per (b,h): 512 threads = 32 channels x 16 element-groups.
// Y read as packed half2 (halves the intermediate's HBM fetch stream).
// Conv = 256(pix) x 32(out) x 64(feat) GEMM via mfma_f32_16x16x32_f16.
__device__ __forceinline__ float fast_atan2(float y, float x) {
    float ax = fabsf(x), ay = fabsf(y);
    float mx = fmaxf(ax, ay), mn = fminf(ax, ay);
    float z = mn * __builtin_amdgcn_rcpf(fmaxf(mx, 1e-37f));
    float z2 = z * z;
    float p = fmaf(z2, -0.01172120f, 0.05265332f);
    p = fmaf(z2, p, -0.11643287f);
    p = fmaf(z2, p, 0.19354346f);
    p = fmaf(z2, p, -0.33262347f);
    p = fmaf(z2, p, 0.99997726f);
    p = p * z;
    float r = (ay > ax) ? (1.5707963f - p) : p;
    r = (x < 0.0f) ? (3.14159265f - r) : r;
    return copysignf(r, y);
}

__global__ __launch_bounds__(512, 4) void frft_rows_conv(
        const unsigned int* __restrict__ Yh,
        const float* __restrict__ alpha_p,
        const float* __restrict__ wmat, float* __restrict__ out) {
    __shared__ float2 s[32 * LSQ];   // per-channel regions; ends as (mag,ang); reused for D
    __shared__ float2 c1l[256], c2l[256], twl[256];
    __shared__ float sscl;
    int tid = threadIdx.x;
    int t = tid & 15, ch = tid >> 4;  // seq's 16 t-threads within one wave

    int b = blockIdx.x >> 8, h = blockIdx.x & 255;
    const unsigned int* xr = Yh + (((long long)(b * C_N + ch)) << 16) + (h << 8);

    float2 v[16];
    #pragma unroll
    for (int n1 = 0; n1 < 16; ++n1) {
        H2U pu; pu.u = xr[16 * (n1 ^ 8) + t];   // ifftshift along W
        v[n1] = make_float2((float)pu.f.lo, (float)pu.f.hi);
    }

    make_tables(tid, alpha_p, c1l, c2l, twl, &sscl);
    __syncthreads();                     // tables ready

    #pragma unroll
    for (int n1 = 0; n1 < 16; ++n1)
        v[n1] = cmul(v[n1], c1l[16 * n1 + t]);

    float2* sp = s + ch * LSQ;
    frft_core16(v, sp, t, c2l, twl);

    // Store (mag, ang/pi): same-wave WAR with core's final reads (all 16 t of
    // this seq are in one wave -> lockstep safe).
    float sc = sscl * (1.0f / 256.0f);
    #pragma unroll
    for (int m1 = 0; m1 < 16; ++m1) {
        float2 o = cmul(v[REG(m1)], c1l[16 * m1 + t]);
        float mg = sc * sqrtf(fmaf(o.x, o.x, o.y * o.y));
        float an = fast_atan2(o.y, o.x) * 0.31830988618f;
        sp[16 * (m1 ^ 8) + t] = make_float2(mg, an);   // index = final pixel w
    }
    __syncthreads();

    // ---- MFMA conv phase ----
    int lane = tid & 63, wv = tid >> 6;
    int q = lane >> 4, l15 = lane & 15;

    // B fragments from global (L2-hot 8KB), f16
    half8 bf[2][2];
    #pragma unroll
    for (int nt = 0; nt < 2; ++nt)
        #pragma unroll
        for (int kt = 0; kt < 2; ++kt) {
            const float* wp = wmat + (nt * 16 + l15) * 64 + kt * 32 + q * 8;
            float4 wa = *(const float4*)wp;
            float4 wb = *(const float4*)(wp + 4);
            bf[nt][kt][0] = (_Float16)wa.x; bf[nt][kt][1] = (_Float16)wa.y;
            bf[nt][kt][2] = (_Float16)wa.z; bf[nt][kt][3] = (_Float16)wa.w;
            bf[nt][kt][4] = (_Float16)wb.x; bf[nt][kt][5] = (_Float16)wb.y;
            bf[nt][kt][6] = (_Float16)wb.z; bf[nt][kt][7] = (_Float16)wb.w;
        }

    f32x4 acc[2][2];
    #pragma unroll
    for (int i = 0; i < 2; ++i)
        #pragma unroll
        for (int j = 0; j < 2; ++j)
            acc[i][j] = (f32x4){0.0f, 0.0f, 0.0f, 0.0f};

    #pragma unroll
    for (int mt2 = 0; mt2 < 2; ++mt2) {
        int mt = wv * 2 + mt2;
        int w = mt * 16 + l15;
        half8 am, aa;
        #pragma unroll
        for (int j = 0; j < 8; ++j) {
            float2 fv = s[(q * 8 + j) * LSQ + w];   // channel q*8+j at pixel w
            am[j] = (_Float16)fv.x;                 // mag -> k = q*8+j
            aa[j] = (_Float16)fv.y;                 // ang -> k = 32 + q*8+j
        }
        #pragma unroll
        for (int nt = 0; nt < 2; ++nt) {
            acc[mt2][nt] = __builtin_amdgcn_mfma_f32_16x16x32_f16(am, bf[nt][0], acc[mt2][nt], 0, 0, 0);
            acc[mt2][nt] = __builtin_amdgcn_mfma_f32_16x16x32_f16(aa, bf[nt][1], acc[mt2][nt], 0, 0, 0);
        }
    }
    __syncthreads();   // all feat reads done before D overwrites s

    // D -> LDS transpose buffer Ob[o][w]
    float* Ob = (float*)s;
    #pragma unroll
    for (int mt2 = 0; mt2 < 2; ++mt2) {
        int mt = wv * 2 + mt2;
        #pragma unroll
        for (int nt = 0; nt < 2; ++nt) {
            int o = nt * 16 + l15;
            *(f32x4*)&Ob[o * LDW + mt * 16 + q * 4] = acc[mt2][nt];
        }
    }
    __syncthreads();

    // coalesced stores: thread -> (o = tid>>4, 4 float4 chunks along w)
    int o2 = tid >> 4, i16 = tid & 15;
    float* ob = out + (((long long)(b * C_N + o2)) << 16) + (h << 8);
    #pragma unroll
    for (int p = 0; p < 4; ++p) {
        int w4 = i16 * 4 + (p << 6);
        f32x4 val = *(f32x4*)&Ob[o2 * LDW + w4];
        *(f32x4*)(ob + w4) = val;
    }
}

// ---------------- launch -----------------------------------------------------
extern "C" void kernel_launch(void* const* d_in, const int* in_sizes, int n_in,
                              void* d_out, int out_size, void* d_ws, size_t ws_size,
                              hipStream_t stream) {
    const float* x     = (const float*)d_in[0];
    const float* alpha = (const float*)d_in[1];
    const float* wmat  = (const float*)d_in[2];
    float* out = (float*)d_out;

    unsigned int* Yh = (unsigned int*)d_ws;   // 32 MiB packed-f16 intermediate

    // Pass 1: FRFT along H on real input (order commutes with W pass).
    frft_cols_real<<<B_N * C_N * (W_N / 32), 512, 0, stream>>>(x, alpha, Yh);

    // Pass 2: FRFT along W + magnitude/phase + MFMA 1x1 conv, fused per (b,h).
    frft_rows_conv<<<B_N * H_N, 512, 0, stream>>>(Yh, alpha, wmat, out);
}